// Round 6
// baseline (251.904 us; speedup 1.0000x reference)
//
#include <hip/hip_runtime.h>
#include <hip/hip_bf16.h>
#include <stdint.h>

#define ALPHA_ 0.2f
#define EPS_   1e-6f

typedef __attribute__((ext_vector_type(8))) short  short8;
typedef __attribute__((ext_vector_type(4))) float  float4v;

static __device__ __forceinline__ unsigned short f2bf(float x) {
    union { float f; unsigned int u; } c; c.f = x;
    return (unsigned short)((c.u + 0x7fffu + ((c.u >> 16) & 1u)) >> 16);
}

// ---------------- K0: WT in MFMA-B-fragment order (for k_wh) ----------------
__global__ __launch_bounds__(256) void k_wt(const float* __restrict__ W,
                                            unsigned short* __restrict__ WTs) {
    const int g  = blockIdx.x * 256 + threadIdx.x;   // 8192 threads
    const int fb = g >> 9, kc = (g >> 6) & 7, l = g & 63;
    const int m = l & 15, quad = l >> 4;
    const int f = fb * 16 + m, d0 = kc * 32 + quad * 8;
    unsigned short v[8];
#pragma unroll
    for (int i = 0; i < 8; ++i) v[i] = f2bf(W[(d0 + i) * 256 + f]);
    uint4 o;
    o.x = (unsigned)v[0] | ((unsigned)v[1] << 16);
    o.y = (unsigned)v[2] | ((unsigned)v[3] << 16);
    o.z = (unsigned)v[4] | ((unsigned)v[5] << 16);
    o.w = (unsigned)v[6] | ((unsigned)v[7] << 16);
    *(uint4*)(WTs + (size_t)g * 8) = o;
}

// ---------------- K1: MFMA Wh = h@W; fused s1/s2; WhS in B-frag order -------
__global__ __launch_bounds__(512) void k_wh(const float* __restrict__ h,
                                            const unsigned short* __restrict__ WTs,
                                            const float* __restrict__ a,
                                            unsigned short* __restrict__ WhS,
                                            float* __restrict__ s1g,
                                            float* __restrict__ s2g) {
    __shared__ __align__(16) unsigned short A_lds[32][264];   // pad 256->264
    __shared__ __align__(16) unsigned short T_lds[256][40];   // [f][j] pad 32->40
    __shared__ float s1p[32], s2p[32];
    const int t    = threadIdx.x;
    const int lane = t & 63;
    const int wv   = t >> 6;              // 0..7
    const int m    = lane & 15;
    const int quad = lane >> 4;
    const int r0   = blockIdx.x * 32;     // 512 blocks
    const int b    = blockIdx.x >> 6;
    const int jc   = blockIdx.x & 63;
    const int j0   = r0 & 2047;

    if (t < 32) { s1p[t] = 0.f; s2p[t] = 0.f; }

    // stage h tile fp32 -> bf16 LDS (coalesced float4)
#pragma unroll
    for (int k = 0; k < 4; ++k) {
        const int flat = t + k * 512;
        const int r  = flat >> 6;
        const int d4 = flat & 63;
        float4v hv = *(const float4v*)(h + (size_t)(r0 + r) * 256 + d4 * 4);
        uint2 pk;
        pk.x = (unsigned)f2bf(hv.x) | ((unsigned)f2bf(hv.y) << 16);
        pk.y = (unsigned)f2bf(hv.z) | ((unsigned)f2bf(hv.w) << 16);
        *(uint2*)&A_lds[r][d4 * 4] = pk;
    }
    __syncthreads();

    const int fbase = wv * 32;
    float4v acc[2][2];
#pragma unroll
    for (int it = 0; it < 2; ++it)
#pragma unroll
        for (int ft = 0; ft < 2; ++ft)
#pragma unroll
            for (int r = 0; r < 4; ++r) acc[it][ft][r] = 0.f;

    const unsigned short* wtb = WTs + (size_t)(wv * 2) * 4096 + lane * 8;

#pragma unroll
    for (int kc = 0; kc < 8; ++kc) {
        short8 af0 = *(const short8*)&A_lds[m][kc * 32 + quad * 8];
        short8 af1 = *(const short8*)&A_lds[16 + m][kc * 32 + quad * 8];
#pragma unroll
        for (int ft = 0; ft < 2; ++ft) {
            short8 bf = *(const short8*)(wtb + (size_t)ft * 4096 + kc * 512);
            acc[0][ft] = __builtin_amdgcn_mfma_f32_16x16x32_bf16(af0, bf, acc[0][ft], 0, 0, 0);
            acc[1][ft] = __builtin_amdgcn_mfma_f32_16x16x32_bf16(af1, bf, acc[1][ft], 0, 0, 0);
        }
    }

    // fused s1/s2
    float a1v[2], a2v[2];
#pragma unroll
    for (int ft = 0; ft < 2; ++ft) {
        a1v[ft] = a[fbase + ft * 16 + m];
        a2v[ft] = a[256 + fbase + ft * 16 + m];
    }
#pragma unroll
    for (int it = 0; it < 2; ++it) {
#pragma unroll
        for (int reg = 0; reg < 4; ++reg) {
            float v1 = 0.f, v2 = 0.f;
#pragma unroll
            for (int ft = 0; ft < 2; ++ft) {
                const float c = acc[it][ft][reg];
                v1 = fmaf(c, a1v[ft], v1);
                v2 = fmaf(c, a2v[ft], v2);
            }
            v1 += __shfl_xor(v1, 1); v2 += __shfl_xor(v2, 1);
            v1 += __shfl_xor(v1, 2); v2 += __shfl_xor(v2, 2);
            v1 += __shfl_xor(v1, 4); v2 += __shfl_xor(v2, 4);
            v1 += __shfl_xor(v1, 8); v2 += __shfl_xor(v2, 8);
            if (m == 0) {
                const int row = it * 16 + quad * 4 + reg;
                atomicAdd(&s1p[row], v1);
                atomicAdd(&s2p[row], v2);
            }
        }
    }

    // C -> T_lds[f][j]
#pragma unroll
    for (int it = 0; it < 2; ++it)
#pragma unroll
        for (int ft = 0; ft < 2; ++ft)
#pragma unroll
            for (int reg = 0; reg < 4; ++reg)
                T_lds[fbase + ft * 16 + m][it * 16 + quad * 4 + reg] =
                    f2bf(acc[it][ft][reg]);

    __syncthreads();   // cross-wave T_lds reads below

    // swizzled store: WhS[(b*64+jc)*16 + fb][l] = T_lds[fb*16 + (l&15)][(l>>4)*8 ..+8]
#pragma unroll
    for (int e = 0; e < 2; ++e) {
        const int idx = e * 512 + t;
        const int fb = idx >> 6, l = idx & 63;
        uint4 v = *(const uint4*)&T_lds[fb * 16 + (l & 15)][(l >> 4) * 8];
        *(uint4*)(WhS + ((size_t)(b * 64 + jc) * 16 + fb) * 512 + l * 8) = v;
    }

    if (t < 32) {
        s1g[(size_t)b * 2048 + j0 + t] = s1p[t];
        s2g[(size_t)b * 2048 + j0 + t] = s2p[t];
    }
}

// ---------------- K3: R5 geometry + one-step-ahead B/adj register pipeline --
// Schedule change ONLY (geometry = R5's fh-merged 512thr/8wave, i-tile 32):
//   per step: [issue B(s+1) + adj(s+2)] -> [MFMA step s, B already in regs]
//   -> [P(s+1) -> pbuf] -> __syncthreads().
// Every load is consumed ONE FULL STEP after issue, so (a) MFMA never waits
// ~300cy on L2 B-reads at point of use, (b) the vmcnt(0) drain inside
// __syncthreads happens when in-flight loads have already had a whole
// MFMA+VALU phase to complete (drain ~free). R1 failed doing this pre-barrier
// with raw barriers (loads got sunk, adj/B competed); this version keeps
// plain __syncthreads and issues loads POST-barrier.
// j-step 64 (32 steps) so the B double-buffer fits in 32 VGPR.
// Explicit unroll-by-2: all A/B register-buffer indices static (no scratch).
static __device__ __forceinline__ unsigned pk2bf(float lo, float hi) {
    float2 v; v.x = lo; v.y = hi;
    union { __hip_bfloat162 h2; unsigned u; } cv;
    cv.h2 = __float22bfloat162_rn(v);
    return cv.u;
}

static __device__ __forceinline__ uint2 pquad(float4v av, float4v s2v,
                                              float s1, float& rs) {
    float e0 = s1 + s2v.x, e1 = s1 + s2v.y, e2 = s1 + s2v.z, e3 = s1 + s2v.w;
    e0 = fmaxf(e0, ALPHA_ * e0); e1 = fmaxf(e1, ALPHA_ * e1);
    e2 = fmaxf(e2, ALPHA_ * e2); e3 = fmaxf(e3, ALPHA_ * e3);
    const float p0 = (av.x + EPS_) * __expf(e0);
    const float p1 = (av.y + EPS_) * __expf(e1);
    const float p2 = (av.z + EPS_) * __expf(e2);
    const float p3 = (av.w + EPS_) * __expf(e3);
    rs += (p0 + p1) + (p2 + p3);
    uint2 r;
    r.x = pk2bf(p0, p1);
    r.y = pk2bf(p2, p3);
    return r;
}

__global__ __launch_bounds__(512, 4) void k_attn(const float* __restrict__ adj,
                                                 const unsigned short* __restrict__ WhS,
                                                 const float* __restrict__ s1g,
                                                 const float* __restrict__ s2g,
                                                 float* __restrict__ out) {
    __shared__ __align__(16) unsigned short pbuf[2][32][72];  // 64 j + pad->72
    __shared__ __align__(16) float s2_lds[2048];              // whole s2 row of b
    __shared__ float rsum_lds[32];

    const int t    = threadIdx.x;
    const int lane = t & 63;
    const int wv   = t >> 6;             // 0..7
    const int m    = lane & 15;
    const int quad = lane >> 4;
    const int blk  = blockIdx.x;
    const int b    = blk & 7;            // XCD-pinned batch
    const int i0   = (blk >> 3) * 32;    // 64 i-tiles of 32 rows

    const int ip = t >> 4;               // 0..31  (i-row)
    const int jq = t & 15;               // 0..15  (j-quad: 4 j each)

    const float* adjp = adj + (size_t)(b * 2048 + i0 + ip) * 2048 + jq * 4;
    const float  s1v  = s1g[(size_t)b * 2048 + i0 + ip];

    const int fbb = wv * 2;              // this wave's first f-block (of 16)
    const unsigned short* whs = WhS + (size_t)b * 64 * 16 * 512 + lane * 8;

    // stage s2 once (8KB; pquad reads become broadcast ds_read)
    {
        const float* s2src = s2g + (size_t)b * 2048;
        *(float4v*)&s2_lds[t * 4] = *(const float4v*)(s2src + t * 4);
    }

    float4v acc[2][2];   // [it][ft]
#pragma unroll
    for (int it = 0; it < 2; ++it)
#pragma unroll
        for (int ft = 0; ft < 2; ++ft)
#pragma unroll
            for (int r = 0; r < 4; ++r) acc[it][ft][r] = 0.f;

    float rs = 0.f;

    // ---- register pipeline state ----
    // even step s: consume bregA (B[s]) + pbuf[0]; P[s+1] from adjB; load B[s+1]->bregB, adj[s+2]->adjA
    // odd  step s: consume bregB (B[s]) + pbuf[1]; P[s+1] from adjA; load B[s+1]->bregA, adj[s+2]->adjB
    short8  bregA[4], bregB[4];   // [kc*2+fb]: B-frags for one 64-j step
    float4v adjA, adjB;

    // prologue: establish invariant for step 0
    adjA = *(const float4v*)(adjp);                 // adj[0]
    adjB = *(const float4v*)(adjp + 64);            // adj[1]
    {
        const unsigned short* bp = whs;             // B[0]: jc=0,1 of fbb,fbb+1
        bregA[0] = *(const short8*)(bp + (size_t)(fbb) * 512);
        bregA[1] = *(const short8*)(bp + (size_t)(fbb + 1) * 512);
        bregA[2] = *(const short8*)(bp + (size_t)(16 + fbb) * 512);
        bregA[3] = *(const short8*)(bp + (size_t)(17 + fbb) * 512);
    }
    __syncthreads();   // s2_lds visible
    {
        float4v s2v = *(const float4v*)&s2_lds[jq * 4];
        uint2 pk = pquad(adjA, s2v, s1v, rs);
        *(uint2*)&pbuf[0][ip][jq * 4] = pk;
    }
    __syncthreads();   // pbuf[0] visible

#define PHASE_LOADS(sB, breg_, adj_, sA)                                        \
    {                                                                           \
        const unsigned short* bp = whs + (size_t)((sB) * 32 + fbb) * 512;       \
        breg_[0] = *(const short8*)bp;                                          \
        breg_[1] = *(const short8*)(bp + 512);                                  \
        breg_[2] = *(const short8*)(bp + 16 * 512);                             \
        breg_[3] = *(const short8*)(bp + 17 * 512);                             \
        adj_ = *(const float4v*)(adjp + (size_t)(sA) * 64);                     \
    }

#define PHASE_MFMA(buf, breg_)                                                  \
    _Pragma("unroll")                                                           \
    for (int kc = 0; kc < 2; ++kc) {                                            \
        short8 af0 = *(const short8*)&pbuf[buf][m][kc * 32 + quad * 8];         \
        short8 af1 = *(const short8*)&pbuf[buf][16 + m][kc * 32 + quad * 8];    \
        acc[0][0] = __builtin_amdgcn_mfma_f32_16x16x32_bf16(af0, breg_[kc*2],   acc[0][0], 0, 0, 0); \
        acc[0][1] = __builtin_amdgcn_mfma_f32_16x16x32_bf16(af0, breg_[kc*2+1], acc[0][1], 0, 0, 0); \
        acc[1][0] = __builtin_amdgcn_mfma_f32_16x16x32_bf16(af1, breg_[kc*2],   acc[1][0], 0, 0, 0); \
        acc[1][1] = __builtin_amdgcn_mfma_f32_16x16x32_bf16(af1, breg_[kc*2+1], acc[1][1], 0, 0, 0); \
    }

#define PHASE_P(sp, adj_, buf)                                                  \
    {                                                                           \
        float4v s2v = *(const float4v*)&s2_lds[(sp) * 64 + jq * 4];             \
        uint2 pk = pquad(adj_, s2v, s1v, rs);                                   \
        *(uint2*)&pbuf[buf][ip][jq * 4] = pk;                                   \
    }

    // main loop: steps 0..29 (loads never wrap: s+2 <= 31)
    for (int s = 0; s < 30; s += 2) {
        // ---- even step s ----
        PHASE_LOADS(s + 1, bregB, adjA, s + 2)
        PHASE_MFMA(0, bregA)
        PHASE_P(s + 1, adjB, 1)
        __syncthreads();
        // ---- odd step s+1 ----
        PHASE_LOADS(s + 2, bregA, adjB, s + 3)
        PHASE_MFMA(1, bregB)
        PHASE_P(s + 2, adjA, 0)
        __syncthreads();
    }
    // tail step 30 (even): no adj load remains
    {
        const unsigned short* bp = whs + (size_t)(31 * 32 + fbb) * 512;
        bregB[0] = *(const short8*)bp;
        bregB[1] = *(const short8*)(bp + 512);
        bregB[2] = *(const short8*)(bp + 16 * 512);
        bregB[3] = *(const short8*)(bp + 17 * 512);
    }
    PHASE_MFMA(0, bregA)
    PHASE_P(31, adjB, 1)
    __syncthreads();
    // tail step 31 (odd): MFMA only
    PHASE_MFMA(1, bregB)

#undef PHASE_LOADS
#undef PHASE_MFMA
#undef PHASE_P

    // rowsum: lanes xor 1,2,4,8 share ip (t = ip*16 + jq)
    rs += __shfl_xor(rs, 1);
    rs += __shfl_xor(rs, 2);
    rs += __shfl_xor(rs, 4);
    rs += __shfl_xor(rs, 8);
    if (jq == 0) rsum_lds[ip] = rs;
    __syncthreads();

    // epilogue: C/D col = lane&15 (f), row = quad*4+reg (i), +16 per it
#pragma unroll
    for (int reg = 0; reg < 4; ++reg) {
        const int row  = quad * 4 + reg;
        const float i0v = 1.0f / rsum_lds[row];
        const float i1v = 1.0f / rsum_lds[16 + row];
#pragma unroll
        for (int ft = 0; ft < 2; ++ft) {
            const int f = wv * 32 + ft * 16 + m;
            out[(size_t)(b * 2048 + i0 + row) * 256 + f]      = acc[0][ft][reg] * i0v;
            out[(size_t)(b * 2048 + i0 + 16 + row) * 256 + f] = acc[1][ft][reg] * i1v;
        }
    }
}

extern "C" void kernel_launch(void* const* d_in, const int* in_sizes, int n_in,
                              void* d_out, int out_size, void* d_ws, size_t ws_size,
                              hipStream_t stream) {
    const float* h   = (const float*)d_in[0];   // (8,2048,256)
    const float* adj = (const float*)d_in[1];   // (8,2048,2048)
    const float* W   = (const float*)d_in[2];   // (256,256)
    const float* a   = (const float*)d_in[3];   // (512,1)
    float* out = (float*)d_out;                 // (8,2048,256)

    unsigned short* WhS = (unsigned short*)d_ws;                        // 8.4 MB
    unsigned short* WTs = (unsigned short*)((char*)d_ws + 8388608);     // 128 KB
    float*          s1  = (float*)((char*)d_ws + 8388608 + 131072);     // 64 KB
    float*          s2  = s1 + 16384;                                   // 64 KB

    k_wt  <<<dim3(32),   dim3(256), 0, stream>>>(W, WTs);
    k_wh  <<<dim3(512),  dim3(512), 0, stream>>>(h, WTs, a, WhS, s1, s2);
    k_attn<<<dim3(512),  dim3(512), 0, stream>>>(adj, WhS, s1, s2, out);
}

// Round 8
// 243.164 us; speedup vs baseline: 1.0359x; 1.0359x over previous
//
#include <hip/hip_runtime.h>
#include <hip/hip_bf16.h>
#include <stdint.h>

#define ALPHA_ 0.2f
#define EPS_   1e-6f

typedef __attribute__((ext_vector_type(8))) short  short8;
typedef __attribute__((ext_vector_type(4))) float  float4v;

static __device__ __forceinline__ unsigned short f2bf(float x) {
    union { float f; unsigned int u; } c; c.f = x;
    return (unsigned short)((c.u + 0x7fffu + ((c.u >> 16) & 1u)) >> 16);
}

// ---------------- K0: WT in MFMA-B-fragment order (for k_wh) ----------------
__global__ __launch_bounds__(256) void k_wt(const float* __restrict__ W,
                                            unsigned short* __restrict__ WTs) {
    const int g  = blockIdx.x * 256 + threadIdx.x;   // 8192 threads
    const int fb = g >> 9, kc = (g >> 6) & 7, l = g & 63;
    const int m = l & 15, quad = l >> 4;
    const int f = fb * 16 + m, d0 = kc * 32 + quad * 8;
    unsigned short v[8];
#pragma unroll
    for (int i = 0; i < 8; ++i) v[i] = f2bf(W[(d0 + i) * 256 + f]);
    uint4 o;
    o.x = (unsigned)v[0] | ((unsigned)v[1] << 16);
    o.y = (unsigned)v[2] | ((unsigned)v[3] << 16);
    o.z = (unsigned)v[4] | ((unsigned)v[5] << 16);
    o.w = (unsigned)v[6] | ((unsigned)v[7] << 16);
    *(uint4*)(WTs + (size_t)g * 8) = o;
}

// ---------------- K1: MFMA Wh = h@W; fused s1/s2; WhS in B-frag order -------
__global__ __launch_bounds__(512) void k_wh(const float* __restrict__ h,
                                            const unsigned short* __restrict__ WTs,
                                            const float* __restrict__ a,
                                            unsigned short* __restrict__ WhS,
                                            float* __restrict__ s1g,
                                            float* __restrict__ s2g) {
    __shared__ __align__(16) unsigned short A_lds[32][264];   // pad 256->264
    __shared__ __align__(16) unsigned short T_lds[256][40];   // [f][j] pad 32->40
    __shared__ float s1p[32], s2p[32];
    const int t    = threadIdx.x;
    const int lane = t & 63;
    const int wv   = t >> 6;              // 0..7
    const int m    = lane & 15;
    const int quad = lane >> 4;
    const int r0   = blockIdx.x * 32;     // 512 blocks
    const int b    = blockIdx.x >> 6;
    const int jc   = blockIdx.x & 63;
    const int j0   = r0 & 2047;

    if (t < 32) { s1p[t] = 0.f; s2p[t] = 0.f; }

    // stage h tile fp32 -> bf16 LDS (coalesced float4)
#pragma unroll
    for (int k = 0; k < 4; ++k) {
        const int flat = t + k * 512;
        const int r  = flat >> 6;
        const int d4 = flat & 63;
        float4v hv = *(const float4v*)(h + (size_t)(r0 + r) * 256 + d4 * 4);
        uint2 pk;
        pk.x = (unsigned)f2bf(hv.x) | ((unsigned)f2bf(hv.y) << 16);
        pk.y = (unsigned)f2bf(hv.z) | ((unsigned)f2bf(hv.w) << 16);
        *(uint2*)&A_lds[r][d4 * 4] = pk;
    }
    __syncthreads();

    const int fbase = wv * 32;
    float4v acc[2][2];
#pragma unroll
    for (int it = 0; it < 2; ++it)
#pragma unroll
        for (int ft = 0; ft < 2; ++ft)
#pragma unroll
            for (int r = 0; r < 4; ++r) acc[it][ft][r] = 0.f;

    const unsigned short* wtb = WTs + (size_t)(wv * 2) * 4096 + lane * 8;

#pragma unroll
    for (int kc = 0; kc < 8; ++kc) {
        short8 af0 = *(const short8*)&A_lds[m][kc * 32 + quad * 8];
        short8 af1 = *(const short8*)&A_lds[16 + m][kc * 32 + quad * 8];
#pragma unroll
        for (int ft = 0; ft < 2; ++ft) {
            short8 bf = *(const short8*)(wtb + (size_t)ft * 4096 + kc * 512);
            acc[0][ft] = __builtin_amdgcn_mfma_f32_16x16x32_bf16(af0, bf, acc[0][ft], 0, 0, 0);
            acc[1][ft] = __builtin_amdgcn_mfma_f32_16x16x32_bf16(af1, bf, acc[1][ft], 0, 0, 0);
        }
    }

    // fused s1/s2
    float a1v[2], a2v[2];
#pragma unroll
    for (int ft = 0; ft < 2; ++ft) {
        a1v[ft] = a[fbase + ft * 16 + m];
        a2v[ft] = a[256 + fbase + ft * 16 + m];
    }
#pragma unroll
    for (int it = 0; it < 2; ++it) {
#pragma unroll
        for (int reg = 0; reg < 4; ++reg) {
            float v1 = 0.f, v2 = 0.f;
#pragma unroll
            for (int ft = 0; ft < 2; ++ft) {
                const float c = acc[it][ft][reg];
                v1 = fmaf(c, a1v[ft], v1);
                v2 = fmaf(c, a2v[ft], v2);
            }
            v1 += __shfl_xor(v1, 1); v2 += __shfl_xor(v2, 1);
            v1 += __shfl_xor(v1, 2); v2 += __shfl_xor(v2, 2);
            v1 += __shfl_xor(v1, 4); v2 += __shfl_xor(v2, 4);
            v1 += __shfl_xor(v1, 8); v2 += __shfl_xor(v2, 8);
            if (m == 0) {
                const int row = it * 16 + quad * 4 + reg;
                atomicAdd(&s1p[row], v1);
                atomicAdd(&s2p[row], v2);
            }
        }
    }

    // C -> T_lds[f][j]
#pragma unroll
    for (int it = 0; it < 2; ++it)
#pragma unroll
        for (int ft = 0; ft < 2; ++ft)
#pragma unroll
            for (int reg = 0; reg < 4; ++reg)
                T_lds[fbase + ft * 16 + m][it * 16 + quad * 4 + reg] =
                    f2bf(acc[it][ft][reg]);

    __syncthreads();   // cross-wave T_lds reads below

    // swizzled store: WhS[(b*64+jc)*16 + fb][l] = T_lds[fb*16 + (l&15)][(l>>4)*8 ..+8]
#pragma unroll
    for (int e = 0; e < 2; ++e) {
        const int idx = e * 512 + t;
        const int fb = idx >> 6, l = idx & 63;
        uint4 v = *(const uint4*)&T_lds[fb * 16 + (l & 15)][(l >> 4) * 8];
        *(uint4*)(WhS + ((size_t)(b * 64 + jc) * 16 + fb) * 512 + l * 8) = v;
    }

    if (t < 32) {
        s1g[(size_t)b * 2048 + j0 + t] = s1p[t];
        s2g[(size_t)b * 2048 + j0 + t] = s2p[t];
    }
}

// ---------------- K3: fh-merged skeleton, 8 steps, post-barrier prefetch ----
// R7 crashed on a geometry bug (8 float4s/thread covering 512 j instead of
// 256; pbuf OOB at 284>268, adj read OOB at col 2076). Fixed decomposition:
// 16 jq-threads x 4 float4 = 256 j/step, j = c*64 + jq*4 (max 255).
// Theory unchanged from R7:
//  - j-step 256 -> 8 steps (halve barrier/drain events; R5->R6 showed
//    per-step fixed cost ~2.1k cy)
//  - adj prefetch issued POST-barrier: at each barrier nothing is in flight
//    (drain free); latency covered by MFMA phase, waited at use in next P.
//  - s2 staged once in LDS (broadcast reads, conflict-free).
// pbuf pad: [268] keeps the proven (+12, row-stride = 6 banks mod 32) class.
static __device__ __forceinline__ unsigned pk2bf(float lo, float hi) {
    float2 v; v.x = lo; v.y = hi;
    union { __hip_bfloat162 h2; unsigned u; } cv;
    cv.h2 = __float22bfloat162_rn(v);
    return cv.u;
}

static __device__ __forceinline__ uint2 pquad(float4v av, float4v s2v,
                                              float s1, float& rs) {
    float e0 = s1 + s2v.x, e1 = s1 + s2v.y, e2 = s1 + s2v.z, e3 = s1 + s2v.w;
    e0 = fmaxf(e0, ALPHA_ * e0); e1 = fmaxf(e1, ALPHA_ * e1);
    e2 = fmaxf(e2, ALPHA_ * e2); e3 = fmaxf(e3, ALPHA_ * e3);
    const float p0 = (av.x + EPS_) * __expf(e0);
    const float p1 = (av.y + EPS_) * __expf(e1);
    const float p2 = (av.z + EPS_) * __expf(e2);
    const float p3 = (av.w + EPS_) * __expf(e3);
    rs += (p0 + p1) + (p2 + p3);
    uint2 r;
    r.x = pk2bf(p0, p1);
    r.y = pk2bf(p2, p3);
    return r;
}

__global__ __launch_bounds__(512, 4) void k_attn(const float* __restrict__ adj,
                                                 const unsigned short* __restrict__ WhS,
                                                 const float* __restrict__ s1g,
                                                 const float* __restrict__ s2g,
                                                 float* __restrict__ out) {
    __shared__ __align__(16) unsigned short pbuf[2][32][268];  // 256 j + pad->268
    __shared__ __align__(16) float s2_lds[2048];               // whole s2 row of b
    __shared__ float rsum_lds[32];

    const int t    = threadIdx.x;
    const int lane = t & 63;
    const int wv   = t >> 6;             // 0..7
    const int m    = lane & 15;
    const int quad = lane >> 4;
    const int blk  = blockIdx.x;
    const int b    = blk & 7;            // XCD-pinned batch
    const int i0   = (blk >> 3) * 32;    // 64 i-tiles of 32 rows

    const int ip = t >> 4;               // 0..31  (i-row)
    const int jq = t & 15;               // 0..15  (j-quad: 4 j each)

    const float* adjp = adj + (size_t)(b * 2048 + i0 + ip) * 2048 + jq * 4;
    const float  s1v  = s1g[(size_t)b * 2048 + i0 + ip];

    const int fbb = wv * 2;              // this wave's first f-block (of 16)
    const unsigned short* whs = WhS + (size_t)b * 64 * 16 * 512;

    // stage s2 once (8KB; pquad reads become broadcast ds_read)
    *(float4v*)&s2_lds[t * 4] = *(const float4v*)(s2g + (size_t)b * 2048 + t * 4);

    float4v acc[2][2];   // [it][ft]
#pragma unroll
    for (int it = 0; it < 2; ++it)
#pragma unroll
        for (int ft = 0; ft < 2; ++ft)
#pragma unroll
            for (int r = 0; r < 4; ++r) acc[it][ft][r] = 0.f;

    float rs = 0.f;

    // prologue: step-0 adj — 4 float4/thread at j = c*64 + jq*4 (16 j/thread)
    float4v adjv[4];
#pragma unroll
    for (int c = 0; c < 4; ++c)
        adjv[c] = *(const float4v*)(adjp + c * 64);

    __syncthreads();   // s2_lds visible

    for (int step = 0; step < 8; ++step) {
        const int cur = step & 1;

        // ---- P(step): fp32 -> bf16 into pbuf[cur] (256 j per i-row) ----
#pragma unroll
        for (int c = 0; c < 4; ++c) {
            float4v s2v = *(const float4v*)&s2_lds[step * 256 + c * 64 + jq * 4];
            uint2 pk = pquad(adjv[c], s2v, s1v, rs);
            *(uint2*)&pbuf[cur][ip][c * 64 + jq * 4] = pk;
        }

        __syncthreads();   // pbuf[cur] visible; NOTHING in flight -> drain free

        // ---- post-barrier prefetch of adj[step+1]; covered by MFMA below ----
        if (step < 7) {
#pragma unroll
            for (int c = 0; c < 4; ++c)
                adjv[c] = *(const float4v*)(adjp + (size_t)(step + 1) * 256 + c * 64);
        }

        // ---- MFMA: 8 K-chunks; B-frags lane-contiguous 1KB L2 reads ----
#pragma unroll
        for (int kc = 0; kc < 8; ++kc) {
            const unsigned short* bp =
                whs + ((size_t)((step * 8 + kc) * 16 + fbb)) * 512 + lane * 8;
            short8 bf0 = *(const short8*)bp;
            short8 bf1 = *(const short8*)(bp + 512);
            short8 af0 = *(const short8*)&pbuf[cur][m][kc * 32 + quad * 8];
            short8 af1 = *(const short8*)&pbuf[cur][16 + m][kc * 32 + quad * 8];
            acc[0][0] = __builtin_amdgcn_mfma_f32_16x16x32_bf16(af0, bf0, acc[0][0], 0, 0, 0);
            acc[0][1] = __builtin_amdgcn_mfma_f32_16x16x32_bf16(af0, bf1, acc[0][1], 0, 0, 0);
            acc[1][0] = __builtin_amdgcn_mfma_f32_16x16x32_bf16(af1, bf0, acc[1][0], 0, 0, 0);
            acc[1][1] = __builtin_amdgcn_mfma_f32_16x16x32_bf16(af1, bf1, acc[1][1], 0, 0, 0);
        }
    }

    // rowsum: lanes xor 1,2,4,8 share ip (t = ip*16 + jq)
    rs += __shfl_xor(rs, 1);
    rs += __shfl_xor(rs, 2);
    rs += __shfl_xor(rs, 4);
    rs += __shfl_xor(rs, 8);
    if (jq == 0) rsum_lds[ip] = rs;
    __syncthreads();

    // epilogue: C/D col = lane&15 (f), row = quad*4+reg (i), +16 per it
#pragma unroll
    for (int reg = 0; reg < 4; ++reg) {
        const int row  = quad * 4 + reg;
        const float i0v = 1.0f / rsum_lds[row];
        const float i1v = 1.0f / rsum_lds[16 + row];
#pragma unroll
        for (int ft = 0; ft < 2; ++ft) {
            const int f = wv * 32 + ft * 16 + m;
            out[(size_t)(b * 2048 + i0 + row) * 256 + f]      = acc[0][ft][reg] * i0v;
            out[(size_t)(b * 2048 + i0 + 16 + row) * 256 + f] = acc[1][ft][reg] * i1v;
        }
    }
}

extern "C" void kernel_launch(void* const* d_in, const int* in_sizes, int n_in,
                              void* d_out, int out_size, void* d_ws, size_t ws_size,
                              hipStream_t stream) {
    const float* h   = (const float*)d_in[0];   // (8,2048,256)
    const float* adj = (const float*)d_in[1];   // (8,2048,2048)
    const float* W   = (const float*)d_in[2];   // (256,256)
    const float* a   = (const float*)d_in[3];   // (512,1)
    float* out = (float*)d_out;                 // (8,2048,256)

    unsigned short* WhS = (unsigned short*)d_ws;                        // 8.4 MB
    unsigned short* WTs = (unsigned short*)((char*)d_ws + 8388608);     // 128 KB
    float*          s1  = (float*)((char*)d_ws + 8388608 + 131072);     // 64 KB
    float*          s2  = s1 + 16384;                                   // 64 KB

    k_wt  <<<dim3(32),   dim3(256), 0, stream>>>(W, WTs);
    k_wh  <<<dim3(512),  dim3(512), 0, stream>>>(h, WTs, a, WhS, s1, s2);
    k_attn<<<dim3(512),  dim3(512), 0, stream>>>(adj, WhS, s1, s2, out);
}

// Round 9
// 231.778 us; speedup vs baseline: 1.0868x; 1.0491x over previous
//
#include <hip/hip_runtime.h>
#include <hip/hip_bf16.h>
#include <stdint.h>

#define ALPHA_ 0.2f
#define EPS_   1e-6f

typedef __attribute__((ext_vector_type(8))) short  short8;
typedef __attribute__((ext_vector_type(4))) float  float4v;

static __device__ __forceinline__ unsigned short f2bf(float x) {
    union { float f; unsigned int u; } c; c.f = x;
    return (unsigned short)((c.u + 0x7fffu + ((c.u >> 16) & 1u)) >> 16);
}

// ---------------- K0: WT in MFMA-B-fragment order (for k_wh) ----------------
__global__ __launch_bounds__(256) void k_wt(const float* __restrict__ W,
                                            unsigned short* __restrict__ WTs) {
    const int g  = blockIdx.x * 256 + threadIdx.x;   // 8192 threads
    const int fb = g >> 9, kc = (g >> 6) & 7, l = g & 63;
    const int m = l & 15, quad = l >> 4;
    const int f = fb * 16 + m, d0 = kc * 32 + quad * 8;
    unsigned short v[8];
#pragma unroll
    for (int i = 0; i < 8; ++i) v[i] = f2bf(W[(d0 + i) * 256 + f]);
    uint4 o;
    o.x = (unsigned)v[0] | ((unsigned)v[1] << 16);
    o.y = (unsigned)v[2] | ((unsigned)v[3] << 16);
    o.z = (unsigned)v[4] | ((unsigned)v[5] << 16);
    o.w = (unsigned)v[6] | ((unsigned)v[7] << 16);
    *(uint4*)(WTs + (size_t)g * 8) = o;
}

// ---------------- K1: MFMA Wh = h@W; fused s1/s2; WhS in B-frag order -------
__global__ __launch_bounds__(512) void k_wh(const float* __restrict__ h,
                                            const unsigned short* __restrict__ WTs,
                                            const float* __restrict__ a,
                                            unsigned short* __restrict__ WhS,
                                            float* __restrict__ s1g,
                                            float* __restrict__ s2g) {
    __shared__ __align__(16) unsigned short A_lds[32][264];   // pad 256->264
    __shared__ __align__(16) unsigned short T_lds[256][40];   // [f][j] pad 32->40
    __shared__ float s1p[32], s2p[32];
    const int t    = threadIdx.x;
    const int lane = t & 63;
    const int wv   = t >> 6;              // 0..7
    const int m    = lane & 15;
    const int quad = lane >> 4;
    const int r0   = blockIdx.x * 32;     // 512 blocks
    const int b    = blockIdx.x >> 6;
    const int jc   = blockIdx.x & 63;
    const int j0   = r0 & 2047;

    if (t < 32) { s1p[t] = 0.f; s2p[t] = 0.f; }

    // stage h tile fp32 -> bf16 LDS (coalesced float4)
#pragma unroll
    for (int k = 0; k < 4; ++k) {
        const int flat = t + k * 512;
        const int r  = flat >> 6;
        const int d4 = flat & 63;
        float4v hv = *(const float4v*)(h + (size_t)(r0 + r) * 256 + d4 * 4);
        uint2 pk;
        pk.x = (unsigned)f2bf(hv.x) | ((unsigned)f2bf(hv.y) << 16);
        pk.y = (unsigned)f2bf(hv.z) | ((unsigned)f2bf(hv.w) << 16);
        *(uint2*)&A_lds[r][d4 * 4] = pk;
    }
    __syncthreads();

    const int fbase = wv * 32;
    float4v acc[2][2];
#pragma unroll
    for (int it = 0; it < 2; ++it)
#pragma unroll
        for (int ft = 0; ft < 2; ++ft)
#pragma unroll
            for (int r = 0; r < 4; ++r) acc[it][ft][r] = 0.f;

    const unsigned short* wtb = WTs + (size_t)(wv * 2) * 4096 + lane * 8;

#pragma unroll
    for (int kc = 0; kc < 8; ++kc) {
        short8 af0 = *(const short8*)&A_lds[m][kc * 32 + quad * 8];
        short8 af1 = *(const short8*)&A_lds[16 + m][kc * 32 + quad * 8];
#pragma unroll
        for (int ft = 0; ft < 2; ++ft) {
            short8 bf = *(const short8*)(wtb + (size_t)ft * 4096 + kc * 512);
            acc[0][ft] = __builtin_amdgcn_mfma_f32_16x16x32_bf16(af0, bf, acc[0][ft], 0, 0, 0);
            acc[1][ft] = __builtin_amdgcn_mfma_f32_16x16x32_bf16(af1, bf, acc[1][ft], 0, 0, 0);
        }
    }

    // fused s1/s2
    float a1v[2], a2v[2];
#pragma unroll
    for (int ft = 0; ft < 2; ++ft) {
        a1v[ft] = a[fbase + ft * 16 + m];
        a2v[ft] = a[256 + fbase + ft * 16 + m];
    }
#pragma unroll
    for (int it = 0; it < 2; ++it) {
#pragma unroll
        for (int reg = 0; reg < 4; ++reg) {
            float v1 = 0.f, v2 = 0.f;
#pragma unroll
            for (int ft = 0; ft < 2; ++ft) {
                const float c = acc[it][ft][reg];
                v1 = fmaf(c, a1v[ft], v1);
                v2 = fmaf(c, a2v[ft], v2);
            }
            v1 += __shfl_xor(v1, 1); v2 += __shfl_xor(v2, 1);
            v1 += __shfl_xor(v1, 2); v2 += __shfl_xor(v2, 2);
            v1 += __shfl_xor(v1, 4); v2 += __shfl_xor(v2, 4);
            v1 += __shfl_xor(v1, 8); v2 += __shfl_xor(v2, 8);
            if (m == 0) {
                const int row = it * 16 + quad * 4 + reg;
                atomicAdd(&s1p[row], v1);
                atomicAdd(&s2p[row], v2);
            }
        }
    }

    // C -> T_lds[f][j]
#pragma unroll
    for (int it = 0; it < 2; ++it)
#pragma unroll
        for (int ft = 0; ft < 2; ++ft)
#pragma unroll
            for (int reg = 0; reg < 4; ++reg)
                T_lds[fbase + ft * 16 + m][it * 16 + quad * 4 + reg] =
                    f2bf(acc[it][ft][reg]);

    __syncthreads();   // cross-wave T_lds reads below

    // swizzled store: WhS[(b*64+jc)*16 + fb][l] = T_lds[fb*16 + (l&15)][(l>>4)*8 ..+8]
#pragma unroll
    for (int e = 0; e < 2; ++e) {
        const int idx = e * 512 + t;
        const int fb = idx >> 6, l = idx & 63;
        uint4 v = *(const uint4*)&T_lds[fb * 16 + (l & 15)][(l >> 4) * 8];
        *(uint4*)(WhS + ((size_t)(b * 64 + jc) * 16 + fb) * 512 + l * 8) = v;
    }

    if (t < 32) {
        s1g[(size_t)b * 2048 + j0 + t] = s1p[t];
        s2g[(size_t)b * 2048 + j0 + t] = s2p[t];
    }
}

// ---------------- K3: R5 (best, ~72us) + covered adj prefetch ---------------
// Ledger: R5(16 steps, pre-barrier prefetch)=72, R6(32 steps)=86,
// R8(8 steps, post-barrier prefetch before B loads)=80. R8's mechanism:
// vmcnt is FIFO, so B-fragment waits forced the older in-flight adj loads
// (HBM ~900cy) to drain first -> MFMA start ate adj latency every step.
// R5's drain exposure: adj issued immediately PRE-barrier -> the barrier's
// vmcnt(0) eats the full HBM latency, and HBM idles during P/MFMA phases
// (measured 1.1 TB/s = 17% of achievable -> bursty adj is the bottleneck).
// Fix (minimal delta off R5):
//  - adjv double-buffered; next step's adj issued at TOP of P phase
//    (sched_barrier(0) pins issue above P). By barrier drain time it has
//    had the whole P phase (~1us) in flight -> drain ~free.
//  - s2 staged once in LDS (broadcast ds_read; 2 fewer vmem queue entries).
//  - B loads stay at point of use AFTER the barrier: queue is clean (adj
//    already drained), exactly R5's proven property.
static __device__ __forceinline__ unsigned pk2bf(float lo, float hi) {
    float2 v; v.x = lo; v.y = hi;
    union { __hip_bfloat162 h2; unsigned u; } cv;
    cv.h2 = __float22bfloat162_rn(v);
    return cv.u;
}

static __device__ __forceinline__ uint2 pquad(float4v av, float4v s2v,
                                              float s1, float& rs) {
    float e0 = s1 + s2v.x, e1 = s1 + s2v.y, e2 = s1 + s2v.z, e3 = s1 + s2v.w;
    e0 = fmaxf(e0, ALPHA_ * e0); e1 = fmaxf(e1, ALPHA_ * e1);
    e2 = fmaxf(e2, ALPHA_ * e2); e3 = fmaxf(e3, ALPHA_ * e3);
    const float p0 = (av.x + EPS_) * __expf(e0);
    const float p1 = (av.y + EPS_) * __expf(e1);
    const float p2 = (av.z + EPS_) * __expf(e2);
    const float p3 = (av.w + EPS_) * __expf(e3);
    rs += (p0 + p1) + (p2 + p3);
    uint2 r;
    r.x = pk2bf(p0, p1);
    r.y = pk2bf(p2, p3);
    return r;
}

__global__ __launch_bounds__(512, 4) void k_attn(const float* __restrict__ adj,
                                                 const unsigned short* __restrict__ WhS,
                                                 const float* __restrict__ s1g,
                                                 const float* __restrict__ s2g,
                                                 float* __restrict__ out) {
    __shared__ __align__(16) unsigned short pbuf[2][32][140];  // pad 128->140
    __shared__ __align__(16) float s2_lds[2048];               // whole s2 row of b
    __shared__ float rsum_lds[32];

    const int t    = threadIdx.x;
    const int lane = t & 63;
    const int wv   = t >> 6;             // 0..7
    const int m    = lane & 15;
    const int quad = lane >> 4;
    const int blk  = blockIdx.x;
    const int b    = blk & 7;            // XCD-pinned batch
    const int i0   = (blk >> 3) * 32;    // 64 i-tiles of 32 rows

    const int ip = t >> 4;               // 0..31  (i-row)
    const int jq = t & 15;               // 0..15  (8 j each)

    const float* adjp = adj + (size_t)(b * 2048 + i0 + ip) * 2048 + jq * 8;
    const float  s1v  = s1g[(size_t)b * 2048 + i0 + ip];

    const int fbb = wv * 2;              // this wave's first f-block (of 16)
    const unsigned short* whs = WhS + (size_t)b * 64 * 16 * 512;

    // stage s2 once (8KB; P-phase reads become broadcast ds_read)
    *(float4v*)&s2_lds[t * 4] = *(const float4v*)(s2g + (size_t)b * 2048 + t * 4);

    float4v acc[2][2];   // [it][ft]
#pragma unroll
    for (int it = 0; it < 2; ++it)
#pragma unroll
        for (int ft = 0; ft < 2; ++ft)
#pragma unroll
            for (int r = 0; r < 4; ++r) acc[it][ft][r] = 0.f;

    float rs = 0.f;

    // prologue: step-0 adj into bufA
    float4v adjA[2], adjB[2];
    adjA[0] = *(const float4v*)(adjp);
    adjA[1] = *(const float4v*)(adjp + 4);

    __syncthreads();   // s2_lds visible (also drains prologue loads - fine)

#define PHASE_P(sp, src, buf)                                                   \
    {                                                                           \
        _Pragma("unroll")                                                       \
        for (int c = 0; c < 2; ++c) {                                           \
            float4v s2v = *(const float4v*)&s2_lds[(sp) * 128 + jq * 8 + c * 4];\
            uint2 pk = pquad(src[c], s2v, s1v, rs);                             \
            *(uint2*)&pbuf[buf][ip][jq * 8 + c * 4] = pk;                       \
        }                                                                       \
    }

#define PHASE_MFMA(sp, buf)                                                     \
    {                                                                           \
        _Pragma("unroll")                                                       \
        for (int kc = 0; kc < 4; ++kc) {                                        \
            const unsigned short* bp =                                          \
                whs + ((size_t)(((sp) * 4 + kc) * 16 + fbb)) * 512 + lane * 8;  \
            short8 bf0 = *(const short8*)bp;                                    \
            short8 bf1 = *(const short8*)(bp + 512);                            \
            short8 af0 = *(const short8*)&pbuf[buf][m][kc * 32 + quad * 8];     \
            short8 af1 = *(const short8*)&pbuf[buf][16 + m][kc * 32 + quad * 8];\
            acc[0][0] = __builtin_amdgcn_mfma_f32_16x16x32_bf16(af0, bf0, acc[0][0], 0, 0, 0); \
            acc[0][1] = __builtin_amdgcn_mfma_f32_16x16x32_bf16(af0, bf1, acc[0][1], 0, 0, 0); \
            acc[1][0] = __builtin_amdgcn_mfma_f32_16x16x32_bf16(af1, bf0, acc[1][0], 0, 0, 0); \
            acc[1][1] = __builtin_amdgcn_mfma_f32_16x16x32_bf16(af1, bf1, acc[1][1], 0, 0, 0); \
        }                                                                       \
    }

    for (int s = 0; s < 16; s += 2) {
        // ---- even step s: prefetch adj[s+1] -> bufB (issued FIRST, covered
        //      by the P phase below before the barrier drains it) ----
        {
            const int ns = s + 1;     // <= 15, never wraps
            adjB[0] = *(const float4v*)(adjp + (size_t)ns * 128);
            adjB[1] = *(const float4v*)(adjp + (size_t)ns * 128 + 4);
        }
        __builtin_amdgcn_sched_barrier(0);   // pin prefetch above P compute
        PHASE_P(s, adjA, 0)
        __syncthreads();                     // drain: adj[s+1] had full P cover
        PHASE_MFMA(s, 0)                     // B queue clean (adj drained)

        // ---- odd step s+1: prefetch adj[s+2] -> bufA ----
        {
            const int ns = (s + 2) & 15;     // wraps only at s=14 (harmless reload)
            adjA[0] = *(const float4v*)(adjp + (size_t)ns * 128);
            adjA[1] = *(const float4v*)(adjp + (size_t)ns * 128 + 4);
        }
        __builtin_amdgcn_sched_barrier(0);
        PHASE_P(s + 1, adjB, 1)
        __syncthreads();
        PHASE_MFMA(s + 1, 1)
    }

#undef PHASE_P
#undef PHASE_MFMA

    // rowsum: lanes xor 1,2,4,8 share ip (t = ip*16 + jq)
    rs += __shfl_xor(rs, 1);
    rs += __shfl_xor(rs, 2);
    rs += __shfl_xor(rs, 4);
    rs += __shfl_xor(rs, 8);
    if (jq == 0) rsum_lds[ip] = rs;
    __syncthreads();

    // epilogue: C/D col = lane&15 (f), row = quad*4+reg (i), +16 per it
#pragma unroll
    for (int reg = 0; reg < 4; ++reg) {
        const int row  = quad * 4 + reg;
        const float i0v = 1.0f / rsum_lds[row];
        const float i1v = 1.0f / rsum_lds[16 + row];
#pragma unroll
        for (int ft = 0; ft < 2; ++ft) {
            const int f = wv * 32 + ft * 16 + m;
            out[(size_t)(b * 2048 + i0 + row) * 256 + f]      = acc[0][ft][reg] * i0v;
            out[(size_t)(b * 2048 + i0 + 16 + row) * 256 + f] = acc[1][ft][reg] * i1v;
        }
    }
}

extern "C" void kernel_launch(void* const* d_in, const int* in_sizes, int n_in,
                              void* d_out, int out_size, void* d_ws, size_t ws_size,
                              hipStream_t stream) {
    const float* h   = (const float*)d_in[0];   // (8,2048,256)
    const float* adj = (const float*)d_in[1];   // (8,2048,2048)
    const float* W   = (const float*)d_in[2];   // (256,256)
    const float* a   = (const float*)d_in[3];   // (512,1)
    float* out = (float*)d_out;                 // (8,2048,256)

    unsigned short* WhS = (unsigned short*)d_ws;                        // 8.4 MB
    unsigned short* WTs = (unsigned short*)((char*)d_ws + 8388608);     // 128 KB
    float*          s1  = (float*)((char*)d_ws + 8388608 + 131072);     // 64 KB
    float*          s2  = s1 + 16384;                                   // 64 KB

    k_wt  <<<dim3(32),   dim3(256), 0, stream>>>(W, WTs);
    k_wh  <<<dim3(512),  dim3(512), 0, stream>>>(h, WTs, a, WhS, s1, s2);
    k_attn<<<dim3(512),  dim3(512), 0, stream>>>(adj, WhS, s1, s2, out);
}